// Round 3
// baseline (4540.837 us; speedup 1.0000x reference)
//
#include <hip/hip_runtime.h>
#include <cstdint>
#include <cstddef>

#define B_  64
#define T_  512
#define I_  512
#define H_  1024

typedef float  f32x4  __attribute__((ext_vector_type(4)));
typedef __bf16 bf16x8 __attribute__((ext_vector_type(8)));
typedef unsigned short us4v __attribute__((ext_vector_type(4)));
typedef unsigned int  u32x4 __attribute__((ext_vector_type(4)));
typedef unsigned long long ull;

__device__ __forceinline__ unsigned short f2bf(float f) {
  unsigned int u = __float_as_uint(f);
  u = (u + 0x7fffu + ((u >> 16) & 1u)) >> 16;   // round-to-nearest-even
  return (unsigned short)u;
}

__device__ __forceinline__ float fast_tanh(float x) {
  x = fminf(10.f, fmaxf(-10.f, x));
  float e = __expf(2.f * x);
  return (e - 1.f) * __builtin_amdgcn_rcpf(e + 1.f);
}

// Agent-scope relaxed atomics: coherent at MALL, bypass per-XCD L2.
__device__ __forceinline__ void st_ag64(ull* p, ull v) {
  __hip_atomic_store(p, v, __ATOMIC_RELAXED, __HIP_MEMORY_SCOPE_AGENT);
}
__device__ __forceinline__ ull ld_ag64(const ull* p) {
  return __hip_atomic_load(p, __ATOMIC_RELAXED, __HIP_MEMORY_SCOPE_AGENT);
}

// ---------------------------------------------------------------------------
// Transpose fp32 [R][C] -> bf16 [C][R] (K-major layouts for MFMA B-operands)
// ---------------------------------------------------------------------------
__global__ __launch_bounds__(256) void k_transpose_cvt(
    const float* __restrict__ in, unsigned short* __restrict__ out, int R, int C) {
  __shared__ float tile[64][65];
  const int tx = threadIdx.x & 63, ty = threadIdx.x >> 6;
  const int c0 = blockIdx.x * 64, r0 = blockIdx.y * 64;
#pragma unroll
  for (int i = 0; i < 16; i++) {
    int r = i * 4 + ty;
    tile[r][tx] = in[(size_t)(r0 + r) * C + c0 + tx];
  }
  __syncthreads();
#pragma unroll
  for (int i = 0; i < 16; i++) {
    int c = i * 4 + ty;
    out[(size_t)(c0 + c) * R + r0 + tx] = f2bf(tile[tx][c]);
  }
}

// ---------------------------------------------------------------------------
// bias = b_ih + b_hh  (tagged hbuf needs NO init: 0xAA poison is never a tag)
// ---------------------------------------------------------------------------
__global__ __launch_bounds__(256) void k_prep(
    const float* __restrict__ bih, const float* __restrict__ bhh,
    float* __restrict__ bias) {
  int gid = blockIdx.x * 256 + threadIdx.x;
  if (gid < H_) bias[gid] = bih[gid] + bhh[gid];
}

// ---------------------------------------------------------------------------
// Phase 1: xw = x @ w_ih + bias  -> written into d_out's hidden_seq region
// ---------------------------------------------------------------------------
__global__ __launch_bounds__(256) void k_gemm_xw(
    const float* __restrict__ x, const unsigned short* __restrict__ wihT,
    const float* __restrict__ bias, float* __restrict__ out) {
  __shared__ __align__(16) unsigned short As[128 * 40];
  __shared__ __align__(16) unsigned short Bs[128 * 40];

  const int tid = threadIdx.x;
  const int bid = blockIdx.x;
  const int tileM = ((bid >> 6) << 3) | (bid & 7);
  const int tileN = (bid >> 3) & 7;
  const int wv = tid >> 6, lane = tid & 63;
  const int row16 = lane & 15, quad = lane >> 4;
  const int m0 = (wv & 1) * 64, n0 = (wv >> 1) * 64;

  f32x4 acc[4][4];
#pragma unroll
  for (int i = 0; i < 4; i++)
#pragma unroll
    for (int j = 0; j < 4; j++) acc[i][j] = (f32x4){0.f, 0.f, 0.f, 0.f};

  const int ar = tid >> 3, ac = (tid & 7) << 2;
  const int br = tid >> 2, bc = (tid & 3) << 3;

#pragma unroll 1
  for (int kt = 0; kt < I_ / 32; kt++) {
    const int k0 = kt * 32;
#pragma unroll
    for (int i = 0; i < 4; i++) {
      int r = ar + i * 32;
      float4 v = *(const float4*)(x + (size_t)(tileM * 128 + r) * I_ + k0 + ac);
      us4v o;
      o.x = f2bf(v.x); o.y = f2bf(v.y); o.z = f2bf(v.z); o.w = f2bf(v.w);
      *(us4v*)(As + r * 40 + ac) = o;
    }
#pragma unroll
    for (int i = 0; i < 2; i++) {
      int r = br + i * 64;
      *(uint4*)(Bs + r * 40 + bc) =
          *(const uint4*)(wihT + (size_t)(tileN * 128 + r) * I_ + k0 + bc);
    }
    __syncthreads();

    bf16x8 af[4], bfr[4];
#pragma unroll
    for (int mt = 0; mt < 4; mt++)
      af[mt] = *(const bf16x8*)(As + (m0 + mt * 16 + row16) * 40 + quad * 8);
#pragma unroll
    for (int nt = 0; nt < 4; nt++)
      bfr[nt] = *(const bf16x8*)(Bs + (n0 + nt * 16 + row16) * 40 + quad * 8);
#pragma unroll
    for (int mt = 0; mt < 4; mt++)
#pragma unroll
      for (int nt = 0; nt < 4; nt++)
        acc[mt][nt] = __builtin_amdgcn_mfma_f32_16x16x32_bf16(
            af[mt], bfr[nt], acc[mt][nt], 0, 0, 0);
    __syncthreads();
  }

#pragma unroll
  for (int mt = 0; mt < 4; mt++)
#pragma unroll
    for (int nt = 0; nt < 4; nt++) {
      int gc = tileN * 128 + n0 + nt * 16 + row16;
      float bv = bias[gc];
#pragma unroll
      for (int r = 0; r < 4; r++) {
        int gr = tileM * 128 + m0 + mt * 16 + quad * 4 + r;
        out[(size_t)gr * H_ + gc] = acc[mt][nt][r] + bv;
      }
    }
}

// ---------------------------------------------------------------------------
// Phase 2: persistent recurrence, XCD-LOCAL groups + L2 fast-path exchange.
//
// 64 blocks x 256 threads = 8 groups x 8 blocks. Group g = blocks with
// bid%8 == g: under round-robin dispatch all 8 land on XCD g and SHARE ONE
// L2. Each block: 8 batches (M=8) x 128 cols (2 N-tiles/wave; A-fragment
// reused across both, so LDS traffic is unchanged). wfrag[2][32] = 256
// VGPRs/lane, resident at __launch_bounds__(256,1) (512-reg budget).
//
// h exchange, tagged 8B words { hi32 = tag = t+1, lo32 = 2 x bf16 }:
//  - FAST path: producer publishes with a plain volatile 8B store (vector
//    L1 is write-through -> lands in the shared XCD L2); consumers poll
//    with volatile loads (sc0: L1-bypass, L2-hit ~200cy instead of the
//    ~1300cy MALL agent-atomic round trip).
//  - SAFETY: producer ALSO publishes every word agent-scope to a MALL
//    mirror. If a consumer's fast polls fail 6 rounds (wrong placement,
//    stale L1/L2 corner), it escalates to agent-scope mirror polls ->
//    bounded slowdown, NEVER a hang, regardless of workgroup->XCD mapping.
// Single-copy atomicity of aligned 8B stores carries tag+payload together
// on both paths; 0xAA ws poison is never a valid tag; ping-pong parity
// slots with the same reuse proof as before (producer reaches slot reuse
// t+2 only after consuming everyone's t+1, which implies t was consumed).
//
// Poll: group slab = 8 batches x 512 pairs = 4096 words; thread owns words
// { i*256 + tid }, q[16]. LDS broadcast 8 rows x 516 dwords (double-buf),
// ONE __syncthreads; A-read row = (lane&15)&7 (rows 8-15 broadcast-read
// duplicates of 0-7 -> free, outputs for quads 2-3 are duplicates, never
// stored). Publish/hidden_seq/xw-prefetch guarded to quad<2.
// ---------------------------------------------------------------------------
__global__ __launch_bounds__(256, 1) void k_scan(
    const unsigned short* __restrict__ whhT,
    unsigned short* __restrict__ hbuf,
    float* __restrict__ out) {
  const int bid = blockIdx.x;
  const int g = bid & 7;            // XCD residue = group id
  const int j = bid >> 3;           // column chunk (128 cols)
  const int tid = threadIdx.x;
  const int wv = tid >> 6, lane = tid & 63;
  const int row = lane & 15, quad = lane >> 4;
  const int bsl = g * 8;            // batch slice base (8 batches/group)
  const int col0 = j * 128 + wv * 16 + row;
  const int col1 = col0 + 64;

  // fast region: [group 8][parity 2][4096 words]; mirror at +65536 words
  ull* hb = (ull*)hbuf;
  const int MIR = 65536;

  // LDS payload broadcast: 2 buffers x 8 rows x 516 u32 (pad 512->516)
  __shared__ __align__(16) unsigned int ldsb[2 * 8 * 516];

  // stationary B-operand: whh[k][col], K-major, 2 N-tiles x 32 K-chunks
  bf16x8 wfrag[2][32];
  {
    const unsigned short* wp0 = whhT + (size_t)col0 * H_ + quad * 8;
    const unsigned short* wp1 = whhT + (size_t)col1 * H_ + quad * 8;
#pragma unroll
    for (int kk = 0; kk < 32; kk++) {
      wfrag[0][kk] = *(const bf16x8*)(wp0 + kk * 32);
      wfrag[1][kk] = *(const bf16x8*)(wp1 + kk * 32);
    }
  }

  const bool pub = (quad < 2);      // lanes owning valid output rows (M=8)
  unsigned int oi[2][4];            // 32-bit float-index into out (fits)
  float xwv[2][4];
  if (pub) {
#pragma unroll
    for (int n = 0; n < 2; n++)
#pragma unroll
      for (int r = 0; r < 4; r++) {
        int b = bsl + quad * 4 + r;
        oi[n][r] = (unsigned int)(b * T_ * H_ + (n ? col1 : col0));
        xwv[n][r] = out[oi[n][r]];
      }
  }

  for (int t = 0; t < T_; ++t) {
    f32x4 acc[2][4];
#pragma unroll
    for (int n = 0; n < 2; n++)
#pragma unroll
      for (int c = 0; c < 4; c++) acc[n][c] = (f32x4){0.f, 0.f, 0.f, 0.f};

    if (t > 0) {
      const ull* fsrc = hb + (size_t)(g * 2 + ((t - 1) & 1)) * 4096;
      const ull* msrc = fsrc + MIR;
      const unsigned int expect = (unsigned int)t;
      ull q[16];
      int rounds = 0;
      for (;;) {
        if (__builtin_expect(rounds < 6, 1)) {
#pragma unroll
          for (int i = 0; i < 16; i++)
            q[i] = *((volatile const ull*)(fsrc + i * 256 + tid));
        } else {
#pragma unroll
          for (int i = 0; i < 16; i++)
            q[i] = ld_ag64(msrc + i * 256 + tid);
        }
        unsigned int bad = 0u;
#pragma unroll
        for (int i = 0; i < 16; i++)
          bad |= ((unsigned int)(q[i] >> 32)) ^ expect;
        if (__builtin_expect(!bad, 1)) break;
        ++rounds;
      }

      // --- LDS broadcast: word i*256+tid -> lds[(w>>9)*516 + (w&511)] ---
      unsigned int* lw = ldsb + (t & 1) * (8 * 516);
#pragma unroll
      for (int i = 0; i < 16; i++)
        lw[(i >> 1) * 516 + (i & 1) * 256 + tid] = (unsigned int)q[i];
      __syncthreads();

      // --- MFMA from LDS A-fragments (A reused across both N-tiles) ---
      const unsigned int* ap = lw + (row & 7) * 516 + quad * 4;
#pragma unroll
      for (int kb = 0; kb < 32; kb++) {
        u32x4 w = *(const u32x4*)(ap + kb * 16);     // ds_read_b128
        bf16x8 a = __builtin_bit_cast(bf16x8, w);
        acc[0][kb & 3] = __builtin_amdgcn_mfma_f32_16x16x32_bf16(
            a, wfrag[0][kb], acc[0][kb & 3], 0, 0, 0);
        acc[1][kb & 3] = __builtin_amdgcn_mfma_f32_16x16x32_bf16(
            a, wfrag[1][kb], acc[1][kb & 3], 0, 0, 0);
      }
    }
    f32x4 accf[2];
    accf[0] = (acc[0][0] + acc[0][1]) + (acc[0][2] + acc[0][3]);
    accf[1] = (acc[1][0] + acc[1][1]) + (acc[1][2] + acc[1][3]);

    if (pub) {
      // h = tanh(acc + xw); publish tagged bf16 pairs on BOTH paths
      ull* fdst = hb + (size_t)(g * 2 + (t & 1)) * 4096;
      ull* mdst = fdst + MIR;
      const ull tagbits = ((ull)(unsigned int)(t + 1)) << 32;
      float hv[2][4];
#pragma unroll
      for (int n = 0; n < 2; n++) {
        const int coln = n ? col1 : col0;
#pragma unroll
        for (int r = 0; r < 4; r++) {
          float h = fast_tanh(accf[n][r] + xwv[n][r]);
          hv[n][r] = h;
          unsigned int myu = (unsigned int)f2bf(h);
          unsigned int pr  = __shfl_xor(myu, 1);
          unsigned int pair = myu | (pr << 16);      // valid on even lanes
          if ((lane & 1) == 0) {
            int w = (quad * 4 + r) * 512 + (coln >> 1);
            *((volatile ull*)(fdst + w)) = tagbits | (ull)pair;  // L2 fast
            st_ag64(mdst + w, tagbits | (ull)pair);              // MALL safe
          }
        }
      }
      __builtin_amdgcn_sched_barrier(0);   // publish issues before out[] I/O

      // off-critical-path: hidden_seq stores, h_T tail, next xw prefetch
#pragma unroll
      for (int n = 0; n < 2; n++) {
        const int coln = n ? col1 : col0;
#pragma unroll
        for (int r = 0; r < 4; r++) {
          out[oi[n][r]] = hv[n][r];
          if (t == T_ - 1) {
            size_t b = (size_t)(bsl + quad * 4 + r);
            out[(size_t)B_ * T_ * H_ + b * H_ + coln] = hv[n][r];
          }
        }
      }
      if (t + 1 < T_) {
#pragma unroll
        for (int n = 0; n < 2; n++)
#pragma unroll
          for (int r = 0; r < 4; r++) {
            oi[n][r] += H_;              // (b*T + t+1)*H + col
            xwv[n][r] = out[oi[n][r]];
          }
      }
    }
  }
}

// ---------------------------------------------------------------------------
extern "C" void kernel_launch(void* const* d_in, const int* in_sizes, int n_in,
                              void* d_out, int out_size, void* d_ws, size_t ws_size,
                              hipStream_t stream) {
  const float* x    = (const float*)d_in[0];
  const float* w_ih = (const float*)d_in[1];
  const float* w_hh = (const float*)d_in[2];
  const float* b_ih = (const float*)d_in[3];
  const float* b_hh = (const float*)d_in[4];
  float* out = (float*)d_out;

  char* ws = (char*)d_ws;
  unsigned short* whhT = (unsigned short*)(ws);                       // 2 MB
  unsigned short* wihT = (unsigned short*)(ws + (2u << 20));          // 1 MB
  float*          bias = (float*)(ws + (3u << 20));                   // 4 KB
  unsigned short* hbuf = (unsigned short*)(ws + (3u << 20) + 4096);   // 1 MB tagged (fast+mirror)

  hipLaunchKernelGGL(k_transpose_cvt, dim3(H_ / 64, H_ / 64), dim3(256), 0, stream,
                     w_hh, whhT, H_, H_);
  hipLaunchKernelGGL(k_transpose_cvt, dim3(H_ / 64, I_ / 64), dim3(256), 0, stream,
                     w_ih, wihT, I_, H_);
  hipLaunchKernelGGL(k_prep, dim3(4), dim3(256), 0, stream, b_ih, b_hh, bias);
  hipLaunchKernelGGL(k_gemm_xw, dim3((B_ * T_ / 128) * (H_ / 128)), dim3(256), 0,
                     stream, x, wihT, bias, out);
  hipLaunchKernelGGL(k_scan, dim3(64), dim3(256), 0, stream, whhT, hbuf, out);
}

// Round 4
// 3541.595 us; speedup vs baseline: 1.2821x; 1.2821x over previous
//
#include <hip/hip_runtime.h>
#include <cstdint>
#include <cstddef>

#define B_  64
#define T_  512
#define I_  512
#define H_  1024

typedef float  f32x4  __attribute__((ext_vector_type(4)));
typedef __bf16 bf16x8 __attribute__((ext_vector_type(8)));
typedef unsigned short us4v __attribute__((ext_vector_type(4)));
typedef unsigned int  u32x4 __attribute__((ext_vector_type(4)));
typedef unsigned long long ull;

__device__ __forceinline__ unsigned short f2bf(float f) {
  unsigned int u = __float_as_uint(f);
  u = (u + 0x7fffu + ((u >> 16) & 1u)) >> 16;   // round-to-nearest-even
  return (unsigned short)u;
}

__device__ __forceinline__ float fast_tanh(float x) {
  x = fminf(10.f, fmaxf(-10.f, x));
  float e = __expf(2.f * x);
  return (e - 1.f) * __builtin_amdgcn_rcpf(e + 1.f);
}

// Agent-scope relaxed atomics: coherent at MALL, bypass per-XCD L2.
__device__ __forceinline__ void st_ag64(ull* p, ull v) {
  __hip_atomic_store(p, v, __ATOMIC_RELAXED, __HIP_MEMORY_SCOPE_AGENT);
}
__device__ __forceinline__ ull ld_ag64(const ull* p) {
  return __hip_atomic_load(p, __ATOMIC_RELAXED, __HIP_MEMORY_SCOPE_AGENT);
}

// ---------------------------------------------------------------------------
// Transpose fp32 [R][C] -> bf16 [C][R] (K-major layouts for MFMA B-operands)
// ---------------------------------------------------------------------------
__global__ __launch_bounds__(256) void k_transpose_cvt(
    const float* __restrict__ in, unsigned short* __restrict__ out, int R, int C) {
  __shared__ float tile[64][65];
  const int tx = threadIdx.x & 63, ty = threadIdx.x >> 6;
  const int c0 = blockIdx.x * 64, r0 = blockIdx.y * 64;
#pragma unroll
  for (int i = 0; i < 16; i++) {
    int r = i * 4 + ty;
    tile[r][tx] = in[(size_t)(r0 + r) * C + c0 + tx];
  }
  __syncthreads();
#pragma unroll
  for (int i = 0; i < 16; i++) {
    int c = i * 4 + ty;
    out[(size_t)(c0 + c) * R + r0 + tx] = f2bf(tile[tx][c]);
  }
}

// ---------------------------------------------------------------------------
// bias = b_ih + b_hh  (tagged hbuf needs NO init: 0xAA poison is never a tag)
// ---------------------------------------------------------------------------
__global__ __launch_bounds__(256) void k_prep(
    const float* __restrict__ bih, const float* __restrict__ bhh,
    float* __restrict__ bias) {
  int gid = blockIdx.x * 256 + threadIdx.x;
  if (gid < H_) bias[gid] = bih[gid] + bhh[gid];
}

// ---------------------------------------------------------------------------
// Phase 1: xw = x @ w_ih + bias  -> written into d_out's hidden_seq region
// XCD-aware swizzle: the 8 blocks sharing an x-tile sit on one XCD.
// ---------------------------------------------------------------------------
__global__ __launch_bounds__(256) void k_gemm_xw(
    const float* __restrict__ x, const unsigned short* __restrict__ wihT,
    const float* __restrict__ bias, float* __restrict__ out) {
  __shared__ __align__(16) unsigned short As[128 * 40];
  __shared__ __align__(16) unsigned short Bs[128 * 40];

  const int tid = threadIdx.x;
  const int bid = blockIdx.x;
  const int tileM = ((bid >> 6) << 3) | (bid & 7);
  const int tileN = (bid >> 3) & 7;
  const int wv = tid >> 6, lane = tid & 63;
  const int row16 = lane & 15, quad = lane >> 4;
  const int m0 = (wv & 1) * 64, n0 = (wv >> 1) * 64;

  f32x4 acc[4][4];
#pragma unroll
  for (int i = 0; i < 4; i++)
#pragma unroll
    for (int j = 0; j < 4; j++) acc[i][j] = (f32x4){0.f, 0.f, 0.f, 0.f};

  const int ar = tid >> 3, ac = (tid & 7) << 2;
  const int br = tid >> 2, bc = (tid & 3) << 3;

#pragma unroll 1
  for (int kt = 0; kt < I_ / 32; kt++) {
    const int k0 = kt * 32;
#pragma unroll
    for (int i = 0; i < 4; i++) {
      int r = ar + i * 32;
      float4 v = *(const float4*)(x + (size_t)(tileM * 128 + r) * I_ + k0 + ac);
      us4v o;
      o.x = f2bf(v.x); o.y = f2bf(v.y); o.z = f2bf(v.z); o.w = f2bf(v.w);
      *(us4v*)(As + r * 40 + ac) = o;
    }
#pragma unroll
    for (int i = 0; i < 2; i++) {
      int r = br + i * 64;
      *(uint4*)(Bs + r * 40 + bc) =
          *(const uint4*)(wihT + (size_t)(tileN * 128 + r) * I_ + k0 + bc);
    }
    __syncthreads();

    bf16x8 af[4], bfr[4];
#pragma unroll
    for (int mt = 0; mt < 4; mt++)
      af[mt] = *(const bf16x8*)(As + (m0 + mt * 16 + row16) * 40 + quad * 8);
#pragma unroll
    for (int nt = 0; nt < 4; nt++)
      bfr[nt] = *(const bf16x8*)(Bs + (n0 + nt * 16 + row16) * 40 + quad * 8);
#pragma unroll
    for (int mt = 0; mt < 4; mt++)
#pragma unroll
      for (int nt = 0; nt < 4; nt++)
        acc[mt][nt] = __builtin_amdgcn_mfma_f32_16x16x32_bf16(
            af[mt], bfr[nt], acc[mt][nt], 0, 0, 0);
    __syncthreads();
  }

#pragma unroll
  for (int mt = 0; mt < 4; mt++)
#pragma unroll
    for (int nt = 0; nt < 4; nt++) {
      int gc = tileN * 128 + n0 + nt * 16 + row16;
      float bv = bias[gc];
#pragma unroll
      for (int r = 0; r < 4; r++) {
        int gr = tileM * 128 + m0 + mt * 16 + quad * 4 + r;
        out[(size_t)gr * H_ + gc] = acc[mt][nt][r] + bv;
      }
    }
}

// ---------------------------------------------------------------------------
// Phase 2: persistent recurrence, XCD-LOCAL groups + L2 fast-path exchange.
//
// 128 blocks x 256 threads = 8 groups x 16 blocks. Group g = { bid : bid%8
// == g }: round-robin dispatch puts all 16 on XCD g, sharing one L2
// (VERIFIED r3: poll FETCH traffic vanished -> polls were same-XCD L2 hits).
// Each block: 8 batches (M=8) x 64 cols (ONE N-tile/wave). wfrag[32] = 128
// VGPRs/lane -- the only weight footprint ever proven register-resident
// (r0: 156 VGPRs). r1 (112) and r3 (220<256 needed) both demoted weights
// and regressed; do NOT grow per-lane weights past 128 regs.
//
// h exchange, tagged 8B words { hi32 = tag = t+1, lo32 = 2 x bf16 }:
//  - FAST: producer publishes via plain volatile 8B store (L1 write-through
//    -> shared XCD L2); consumers poll volatile loads (L1-bypass, L2 hit
//    ~200cy vs ~1300cy MALL agent round trip).
//  - SAFETY: every word is ALSO published agent-scope to a MALL mirror; a
//    consumer escalates to mirror polls after 4 failed fast rounds ->
//    bounded slowdown, never a hang, regardless of block->XCD mapping.
// Single-copy atomicity of aligned 8B stores carries tag+payload together
// on both paths; 0xAA poison is never a valid tag; ping-pong parity slots
// (producer reaches slot reuse t+2 only after consuming everyone's t+1,
// which implies t was consumed). Poll at loop top (r2 proved early-issue
// only adds a round trip).
//
// Group slab = 8 batches x 512 pairs = 4096 words; thread owns words
// { i*256 + tid }, q[16] (32 regs). LDS broadcast 2 x 8 rows x 516 dwords,
// ONE __syncthreads; A-read row = (lane&15)&7 (rows 8-15 broadcast-read
// duplicates -> quads 2-3 compute duplicate batches, never stored).
// Publish / hidden_seq stores / xw prefetch guarded to quad<2.
// ---------------------------------------------------------------------------
__global__ __launch_bounds__(256, 1) void k_scan(
    const unsigned short* __restrict__ whhT,
    unsigned short* __restrict__ hbuf,
    float* __restrict__ out) {
  const int bid = blockIdx.x;
  const int g = bid & 7;            // XCD residue = group id
  const int j = bid >> 3;           // column chunk (64 cols), 0..15
  const int tid = threadIdx.x;
  const int wv = tid >> 6, lane = tid & 63;
  const int row = lane & 15, quad = lane >> 4;
  const int bsl = g * 8;            // batch slice base (8 batches/group)
  const int mycol = j * 64 + wv * 16 + row;

  // fast region: [group 8][parity 2][4096 words]; mirror at +65536 words
  ull* hb = (ull*)hbuf;
  const int MIR = 65536;

  // LDS payload broadcast: 2 buffers x 8 rows x 516 u32 (pad 512->516)
  __shared__ __align__(16) unsigned int ldsb[2 * 8 * 516];

  // stationary B-operand: whh[k][mycol], K-major, 32 K-chunks = 128 VGPRs
  bf16x8 wfrag[32];
  {
    const unsigned short* wp = whhT + (size_t)mycol * H_ + quad * 8;
#pragma unroll
    for (int kk = 0; kk < 32; kk++)
      wfrag[kk] = *(const bf16x8*)(wp + kk * 32);
  }

  const bool pub = (quad < 2);      // lanes owning valid output rows (M=8)
  unsigned int oi[4];               // 32-bit float-index into out (fits)
  float xwv[4];
  if (pub) {
#pragma unroll
    for (int r = 0; r < 4; r++) {
      int b = bsl + quad * 4 + r;
      oi[r] = (unsigned int)(b * T_ * H_ + mycol);
      xwv[r] = out[oi[r]];
    }
  }

  for (int t = 0; t < T_; ++t) {
    f32x4 acc[4];
#pragma unroll
    for (int c = 0; c < 4; c++) acc[c] = (f32x4){0.f, 0.f, 0.f, 0.f};

    if (t > 0) {
      const ull* fsrc = hb + (size_t)(g * 2 + ((t - 1) & 1)) * 4096;
      const ull* msrc = fsrc + MIR;
      const unsigned int expect = (unsigned int)t;
      ull q[16];
      int rounds = 0;
      for (;;) {
        if (__builtin_expect(rounds < 4, 1)) {
#pragma unroll
          for (int i = 0; i < 16; i++)
            q[i] = *((volatile const ull*)(fsrc + i * 256 + tid));
        } else {
#pragma unroll
          for (int i = 0; i < 16; i++)
            q[i] = ld_ag64(msrc + i * 256 + tid);
        }
        unsigned int bad = 0u;
#pragma unroll
        for (int i = 0; i < 16; i++)
          bad |= ((unsigned int)(q[i] >> 32)) ^ expect;
        if (__builtin_expect(!bad, 1)) break;
        ++rounds;
      }

      // --- LDS broadcast: word w=i*256+tid -> lds[(w>>9)*516 + (w&511)] ---
      unsigned int* lw = ldsb + (t & 1) * (8 * 516);
#pragma unroll
      for (int i = 0; i < 16; i++)
        lw[(i >> 1) * 516 + (i & 1) * 256 + tid] = (unsigned int)q[i];
      __syncthreads();

      // --- MFMA from LDS A-fragments (rows 8-15 dup rows 0-7) ---
      const unsigned int* ap = lw + (row & 7) * 516 + quad * 4;
#pragma unroll
      for (int kb = 0; kb < 32; kb++) {
        u32x4 w = *(const u32x4*)(ap + kb * 16);     // ds_read_b128
        bf16x8 a = __builtin_bit_cast(bf16x8, w);
        acc[kb & 3] = __builtin_amdgcn_mfma_f32_16x16x32_bf16(
            a, wfrag[kb], acc[kb & 3], 0, 0, 0);
      }
    }
    f32x4 accf = (acc[0] + acc[1]) + (acc[2] + acc[3]);

    if (pub) {
      // h = tanh(acc + xw); publish tagged bf16 pairs on BOTH paths
      ull* fdst = hb + (size_t)(g * 2 + (t & 1)) * 4096;
      ull* mdst = fdst + MIR;
      const ull tagbits = ((ull)(unsigned int)(t + 1)) << 32;
      float hv[4];
#pragma unroll
      for (int r = 0; r < 4; r++) {
        float h = fast_tanh(accf[r] + xwv[r]);
        hv[r] = h;
        unsigned int myu = (unsigned int)f2bf(h);
        unsigned int pr  = __shfl_xor(myu, 1);
        unsigned int pair = myu | (pr << 16);        // valid on even lanes
        if ((lane & 1) == 0) {
          int w = (quad * 4 + r) * 512 + (mycol >> 1);
          *((volatile ull*)(fdst + w)) = tagbits | (ull)pair;  // L2 fast
          st_ag64(mdst + w, tagbits | (ull)pair);              // MALL safe
        }
      }
      __builtin_amdgcn_sched_barrier(0);   // publish issues before out[] I/O

      // off-critical-path: hidden_seq stores, h_T tail, next xw prefetch
#pragma unroll
      for (int r = 0; r < 4; r++) {
        out[oi[r]] = hv[r];
        if (t == T_ - 1) {
          size_t b = (size_t)(bsl + quad * 4 + r);
          out[(size_t)B_ * T_ * H_ + b * H_ + mycol] = hv[r];
        }
      }
      if (t + 1 < T_) {
#pragma unroll
        for (int r = 0; r < 4; r++) {
          oi[r] += H_;                 // (b*T + t+1)*H + mycol
          xwv[r] = out[oi[r]];
        }
      }
    }
  }
}

// ---------------------------------------------------------------------------
extern "C" void kernel_launch(void* const* d_in, const int* in_sizes, int n_in,
                              void* d_out, int out_size, void* d_ws, size_t ws_size,
                              hipStream_t stream) {
  const float* x    = (const float*)d_in[0];
  const float* w_ih = (const float*)d_in[1];
  const float* w_hh = (const float*)d_in[2];
  const float* b_ih = (const float*)d_in[3];
  const float* b_hh = (const float*)d_in[4];
  float* out = (float*)d_out;

  char* ws = (char*)d_ws;
  unsigned short* whhT = (unsigned short*)(ws);                       // 2 MB
  unsigned short* wihT = (unsigned short*)(ws + (2u << 20));          // 1 MB
  float*          bias = (float*)(ws + (3u << 20));                   // 4 KB
  unsigned short* hbuf = (unsigned short*)(ws + (3u << 20) + 4096);   // 1 MB tagged (fast+mirror)

  hipLaunchKernelGGL(k_transpose_cvt, dim3(H_ / 64, H_ / 64), dim3(256), 0, stream,
                     w_hh, whhT, H_, H_);
  hipLaunchKernelGGL(k_transpose_cvt, dim3(H_ / 64, I_ / 64), dim3(256), 0, stream,
                     w_ih, wihT, I_, H_);
  hipLaunchKernelGGL(k_prep, dim3(4), dim3(256), 0, stream, b_ih, b_hh, bias);
  hipLaunchKernelGGL(k_gemm_xw, dim3((B_ * T_ / 128) * (H_ / 128)), dim3(256), 0,
                     stream, x, wihT, bias, out);
  hipLaunchKernelGGL(k_scan, dim3(128), dim3(256), 0, stream, whhT, hbuf, out);
}

// Round 6
// 3536.264 us; speedup vs baseline: 1.2841x; 1.0015x over previous
//
#include <hip/hip_runtime.h>
#include <cstdint>
#include <cstddef>

#define B_  64
#define T_  512
#define I_  512
#define H_  1024

typedef float  f32x4  __attribute__((ext_vector_type(4)));
typedef __bf16 bf16x8 __attribute__((ext_vector_type(8)));
typedef unsigned short us4v __attribute__((ext_vector_type(4)));
typedef unsigned int  u32x4 __attribute__((ext_vector_type(4)));
typedef unsigned long long ull;

__device__ __forceinline__ unsigned short f2bf(float f) {
  unsigned int u = __float_as_uint(f);
  u = (u + 0x7fffu + ((u >> 16) & 1u)) >> 16;   // round-to-nearest-even
  return (unsigned short)u;
}

__device__ __forceinline__ float fast_tanh(float x) {
  x = fminf(10.f, fmaxf(-10.f, x));
  float e = __expf(2.f * x);
  return (e - 1.f) * __builtin_amdgcn_rcpf(e + 1.f);
}

// Agent-scope relaxed atomics: coherent at MALL, bypass per-XCD L2.
__device__ __forceinline__ void st_ag64(ull* p, ull v) {
  __hip_atomic_store(p, v, __ATOMIC_RELAXED, __HIP_MEMORY_SCOPE_AGENT);
}
__device__ __forceinline__ ull ld_ag64(const ull* p) {
  return __hip_atomic_load(p, __ATOMIC_RELAXED, __HIP_MEMORY_SCOPE_AGENT);
}

// ---------------------------------------------------------------------------
// Transpose fp32 [R][C] -> bf16 [C][R] (K-major layouts for MFMA B-operands)
// ---------------------------------------------------------------------------
__global__ __launch_bounds__(256) void k_transpose_cvt(
    const float* __restrict__ in, unsigned short* __restrict__ out, int R, int C) {
  __shared__ float tile[64][65];
  const int tx = threadIdx.x & 63, ty = threadIdx.x >> 6;
  const int c0 = blockIdx.x * 64, r0 = blockIdx.y * 64;
#pragma unroll
  for (int i = 0; i < 16; i++) {
    int r = i * 4 + ty;
    tile[r][tx] = in[(size_t)(r0 + r) * C + c0 + tx];
  }
  __syncthreads();
#pragma unroll
  for (int i = 0; i < 16; i++) {
    int c = i * 4 + ty;
    out[(size_t)(c0 + c) * R + r0 + tx] = f2bf(tile[tx][c]);
  }
}

// ---------------------------------------------------------------------------
// bias = b_ih + b_hh  (tagged hbuf needs NO init: 0xAA poison is never a tag)
// ---------------------------------------------------------------------------
__global__ __launch_bounds__(256) void k_prep(
    const float* __restrict__ bih, const float* __restrict__ bhh,
    float* __restrict__ bias) {
  int gid = blockIdx.x * 256 + threadIdx.x;
  if (gid < H_) bias[gid] = bih[gid] + bhh[gid];
}

// ---------------------------------------------------------------------------
// Phase 1: xw = x @ w_ih + bias  -> written into d_out's hidden_seq region
// XCD-aware swizzle: the 8 blocks sharing an x-tile sit on one XCD.
// ---------------------------------------------------------------------------
__global__ __launch_bounds__(256) void k_gemm_xw(
    const float* __restrict__ x, const unsigned short* __restrict__ wihT,
    const float* __restrict__ bias, float* __restrict__ out) {
  __shared__ __align__(16) unsigned short As[128 * 40];
  __shared__ __align__(16) unsigned short Bs[128 * 40];

  const int tid = threadIdx.x;
  const int bid = blockIdx.x;
  const int tileM = ((bid >> 6) << 3) | (bid & 7);
  const int tileN = (bid >> 3) & 7;
  const int wv = tid >> 6, lane = tid & 63;
  const int row16 = lane & 15, quad = lane >> 4;
  const int m0 = (wv & 1) * 64, n0 = (wv >> 1) * 64;

  f32x4 acc[4][4];
#pragma unroll
  for (int i = 0; i < 4; i++)
#pragma unroll
    for (int j = 0; j < 4; j++) acc[i][j] = (f32x4){0.f, 0.f, 0.f, 0.f};

  const int ar = tid >> 3, ac = (tid & 7) << 2;
  const int br = tid >> 2, bc = (tid & 3) << 3;

#pragma unroll 1
  for (int kt = 0; kt < I_ / 32; kt++) {
    const int k0 = kt * 32;
#pragma unroll
    for (int i = 0; i < 4; i++) {
      int r = ar + i * 32;
      float4 v = *(const float4*)(x + (size_t)(tileM * 128 + r) * I_ + k0 + ac);
      us4v o;
      o.x = f2bf(v.x); o.y = f2bf(v.y); o.z = f2bf(v.z); o.w = f2bf(v.w);
      *(us4v*)(As + r * 40 + ac) = o;
    }
#pragma unroll
    for (int i = 0; i < 2; i++) {
      int r = br + i * 64;
      *(uint4*)(Bs + r * 40 + bc) =
          *(const uint4*)(wihT + (size_t)(tileN * 128 + r) * I_ + k0 + bc);
    }
    __syncthreads();

    bf16x8 af[4], bfr[4];
#pragma unroll
    for (int mt = 0; mt < 4; mt++)
      af[mt] = *(const bf16x8*)(As + (m0 + mt * 16 + row16) * 40 + quad * 8);
#pragma unroll
    for (int nt = 0; nt < 4; nt++)
      bfr[nt] = *(const bf16x8*)(Bs + (n0 + nt * 16 + row16) * 40 + quad * 8);
#pragma unroll
    for (int mt = 0; mt < 4; mt++)
#pragma unroll
      for (int nt = 0; nt < 4; nt++)
        acc[mt][nt] = __builtin_amdgcn_mfma_f32_16x16x32_bf16(
            af[mt], bfr[nt], acc[mt][nt], 0, 0, 0);
    __syncthreads();
  }

#pragma unroll
  for (int mt = 0; mt < 4; mt++)
#pragma unroll
    for (int nt = 0; nt < 4; nt++) {
      int gc = tileN * 128 + n0 + nt * 16 + row16;
      float bv = bias[gc];
#pragma unroll
      for (int r = 0; r < 4; r++) {
        int gr = tileM * 128 + m0 + mt * 16 + quad * 4 + r;
        out[(size_t)gr * H_ + gc] = acc[mt][nt][r] + bv;
      }
    }
}

// ---------------------------------------------------------------------------
// Phase 2: persistent recurrence, XCD-LOCAL groups + L2 fast-path exchange.
//
// 128 blocks x 256 threads = 8 groups x 16 blocks; group g = { bid%8 == g }
// -> all on XCD g, one shared L2 (VERIFIED r3/r4: poll FETCH vanished).
// Each block: 8 batches x 64 cols, wfrag[32] = 128 VGPRs/lane.
//
// REGISTER PIN (the r4 fix, asm-poll variant of r5 dropped for compile):
// r1/r3/r4 all showed the allocator REMATERIALIZES wfrag loads inside the
// t-loop instead of keeping them resident (legal for const __restrict__
// memory), costing ~512B/lane/step of L2 traffic that also contends with
// the poll storm on the same XCD L2 (r4: VGPR_Count=136 proves demotion).
// The empty asm "+v" barrier after the load makes the values asm-defined:
// remat is now illegal, so they MUST stay in VGPRs (budget 512 at (256,1),
// ~220 live -> no spill). Check: VGPR_Count must jump to >=200.
//
// h exchange, tagged 8B words { hi32 = tag = t+1, lo32 = 2 x bf16 }:
//  - FAST: producer publishes volatile 8B store (write-through L1 -> XCD
//    L2); consumers poll volatile 8B loads (r4-proven codegen). s_sleep(1)
//    backoff on failed rounds damps the shared-L2 poll storm.
//  - SAFETY: every word also published agent-scope to a MALL mirror;
//    consumer escalates to mirror polls after 4 failed fast rounds ->
//    bounded slowdown, never a hang, for any block->XCD mapping.
// Single-copy atomicity of aligned 8B stores carries tag+payload together;
// 0xAA poison is never a valid tag; ping-pong parity slots (producer
// reaches slot reuse t+2 only after consuming everyone's t+1). Poll at
// loop top (r2: early-issue only adds a round trip).
//
// LDS broadcast row stride 516 -> 520 dwords: bank(r,q) = (8r+4q)%32 ->
// exactly 2-way aliasing on ds_read_b128 (free, m136) vs 4-way at 516
// (r4: 3.35e7 conflict cycles).
// ---------------------------------------------------------------------------
#define LST 520   // LDS row stride in dwords

__global__ __launch_bounds__(256, 1) void k_scan(
    const unsigned short* __restrict__ whhT,
    unsigned short* __restrict__ hbuf,
    float* __restrict__ out) {
  const int bid = blockIdx.x;
  const int g = bid & 7;            // XCD residue = group id
  const int j = bid >> 3;           // column chunk (64 cols), 0..15
  const int tid = threadIdx.x;
  const int wv = tid >> 6, lane = tid & 63;
  const int row = lane & 15, quad = lane >> 4;
  const int bsl = g * 8;            // batch slice base (8 batches/group)
  const int mycol = j * 64 + wv * 16 + row;

  // fast region: [group 8][parity 2][4096 words]; mirror at +65536 words
  ull* hb = (ull*)hbuf;
  const int MIR = 65536;

  // LDS payload broadcast: 2 buffers x 8 rows x 520 u32
  __shared__ __align__(16) unsigned int ldsb[2 * 8 * LST];

  // stationary B-operand: whh[k][mycol], K-major, 32 K-chunks = 128 VGPRs
  bf16x8 wfrag[32];
  {
    const unsigned short* wp = whhT + (size_t)mycol * H_ + quad * 8;
#pragma unroll
    for (int kk = 0; kk < 32; kk++)
      wfrag[kk] = *(const bf16x8*)(wp + kk * 32);
  }
  // PIN: make wfrag asm-defined -> rematerialization illegal, must stay
  // in registers for the whole kernel.
#pragma unroll
  for (int kk = 0; kk < 32; kk++)
    asm volatile("" : "+v"(wfrag[kk]));

  const bool pub = (quad < 2);      // lanes owning valid output rows (M=8)
  unsigned int oi[4];               // 32-bit float-index into out (fits)
  float xwv[4];
  if (pub) {
#pragma unroll
    for (int r = 0; r < 4; r++) {
      int b = bsl + quad * 4 + r;
      oi[r] = (unsigned int)(b * T_ * H_ + mycol);
      xwv[r] = out[oi[r]];
    }
  }

  for (int t = 0; t < T_; ++t) {
    f32x4 acc[4];
#pragma unroll
    for (int c = 0; c < 4; c++) acc[c] = (f32x4){0.f, 0.f, 0.f, 0.f};

    if (t > 0) {
      const ull* fsrc = hb + (size_t)(g * 2 + ((t - 1) & 1)) * 4096;
      const ull* msrc = fsrc + MIR;
      const unsigned int expect = (unsigned int)t;
      ull q[16];
      int rounds = 0;
      for (;;) {
        if (__builtin_expect(rounds < 4, 1)) {
#pragma unroll
          for (int i = 0; i < 16; i++)
            q[i] = *((volatile const ull*)(fsrc + i * 256 + tid));
        } else {
#pragma unroll
          for (int i = 0; i < 16; i++)
            q[i] = ld_ag64(msrc + i * 256 + tid);
        }
        unsigned int bad = 0u;
#pragma unroll
        for (int i = 0; i < 16; i++)
          bad |= ((unsigned int)(q[i] >> 32)) ^ expect;
        if (__builtin_expect(!bad, 1)) break;
        ++rounds;
        __builtin_amdgcn_s_sleep(1);   // damp the L2 poll storm
      }

      // --- LDS broadcast: word w=i*256+tid -> lds[(w>>9)*LST + (w&511)] ---
      unsigned int* lw = ldsb + (t & 1) * (8 * LST);
#pragma unroll
      for (int i = 0; i < 16; i++)
        lw[(i >> 1) * LST + (i & 1) * 256 + tid] = (unsigned int)q[i];
      __syncthreads();

      // --- MFMA from LDS A-fragments (rows 8-15 dup rows 0-7) ---
      const unsigned int* ap = lw + (row & 7) * LST + quad * 4;
#pragma unroll
      for (int kb = 0; kb < 32; kb++) {
        u32x4 w = *(const u32x4*)(ap + kb * 16);     // ds_read_b128
        bf16x8 a = __builtin_bit_cast(bf16x8, w);
        acc[kb & 3] = __builtin_amdgcn_mfma_f32_16x16x32_bf16(
            a, wfrag[kb], acc[kb & 3], 0, 0, 0);
      }
    }
    f32x4 accf = (acc[0] + acc[1]) + (acc[2] + acc[3]);

    if (pub) {
      // h = tanh(acc + xw); publish tagged bf16 pairs on BOTH paths
      ull* fdst = hb + (size_t)(g * 2 + (t & 1)) * 4096;
      ull* mdst = fdst + MIR;
      const ull tagbits = ((ull)(unsigned int)(t + 1)) << 32;
      float hv[4];
#pragma unroll
      for (int r = 0; r < 4; r++) {
        float h = fast_tanh(accf[r] + xwv[r]);
        hv[r] = h;
        unsigned int myu = (unsigned int)f2bf(h);
        unsigned int pr  = __shfl_xor(myu, 1);
        unsigned int pair = myu | (pr << 16);        // valid on even lanes
        if ((lane & 1) == 0) {
          int w = (quad * 4 + r) * 512 + (mycol >> 1);
          *((volatile ull*)(fdst + w)) = tagbits | (ull)pair;  // L2 fast
          st_ag64(mdst + w, tagbits | (ull)pair);              // MALL safe
        }
      }
      __builtin_amdgcn_sched_barrier(0);   // publish issues before out[] I/O

      // off-critical-path: hidden_seq stores, h_T tail, next xw prefetch
#pragma unroll
      for (int r = 0; r < 4; r++) {
        out[oi[r]] = hv[r];
        if (t == T_ - 1) {
          size_t b = (size_t)(bsl + quad * 4 + r);
          out[(size_t)B_ * T_ * H_ + b * H_ + mycol] = hv[r];
        }
      }
      if (t + 1 < T_) {
#pragma unroll
        for (int r = 0; r < 4; r++) {
          oi[r] += H_;                 // (b*T + t+1)*H + mycol
          xwv[r] = out[oi[r]];
        }
      }
    }
  }
}

// ---------------------------------------------------------------------------
extern "C" void kernel_launch(void* const* d_in, const int* in_sizes, int n_in,
                              void* d_out, int out_size, void* d_ws, size_t ws_size,
                              hipStream_t stream) {
  const float* x    = (const float*)d_in[0];
  const float* w_ih = (const float*)d_in[1];
  const float* w_hh = (const float*)d_in[2];
  const float* b_ih = (const float*)d_in[3];
  const float* b_hh = (const float*)d_in[4];
  float* out = (float*)d_out;

  char* ws = (char*)d_ws;
  unsigned short* whhT = (unsigned short*)(ws);                       // 2 MB
  unsigned short* wihT = (unsigned short*)(ws + (2u << 20));          // 1 MB
  float*          bias = (float*)(ws + (3u << 20));                   // 4 KB
  unsigned short* hbuf = (unsigned short*)(ws + (3u << 20) + 4096);   // 1 MB tagged (fast+mirror)

  hipLaunchKernelGGL(k_transpose_cvt, dim3(H_ / 64, H_ / 64), dim3(256), 0, stream,
                     w_hh, whhT, H_, H_);
  hipLaunchKernelGGL(k_transpose_cvt, dim3(H_ / 64, I_ / 64), dim3(256), 0, stream,
                     w_ih, wihT, I_, H_);
  hipLaunchKernelGGL(k_prep, dim3(4), dim3(256), 0, stream, b_ih, b_hh, bias);
  hipLaunchKernelGGL(k_gemm_xw, dim3((B_ * T_ / 128) * (H_ / 128)), dim3(256), 0,
                     stream, x, wihT, bias, out);
  hipLaunchKernelGGL(k_scan, dim3(128), dim3(256), 0, stream, whhT, hbuf, out);
}